// Round 6
// baseline (102.897 us; speedup 1.0000x reference)
//
#include <hip/hip_runtime.h>

#define S_ROWS 2048
#define RO_ROWS 8192
#define HEADS 8
#define HDIM 32
#define ROWLEN 256           // HEADS * HDIM
#define NB_S (S_ROWS / 16)   // 128 fragment-blocks of s
#define NB_RO (RO_ROWS / 16) // 512 fragment-blocks of ro

typedef __attribute__((ext_vector_type(8))) short bf16x8;
typedef __attribute__((ext_vector_type(4))) float f32x4;
typedef __attribute__((ext_vector_type(4))) short s16x4;

__device__ __forceinline__ short f32_to_bf16_rne(float f) {
    union { float f; unsigned u; } v; v.f = f;
    return (short)((v.u + 0x7fffu + ((v.u >> 16) & 1u)) >> 16);
}

// Normalize every 32-elem head vector; emit bf16 fragment-major
// [H][N/16][16][32] (one 16x32 MFMA fragment = contiguous 1 KiB).
// Thread mapping puts (dg, r16) in the LOW bits so each wave's 64 stores are
// one contiguous 512B segment; reads are 8 x 128B full-line segments.
// Threads sharing a head vector differ only in dg = lane&7 -> shfl_xor 1/2/4.
__global__ __launch_bounds__(256) void mhd_normalize(const float* __restrict__ s,
                                                     const float* __restrict__ ro,
                                                     short* __restrict__ sF,
                                                     short* __restrict__ roF) {
    const int v   = blockIdx.x * 256 + threadIdx.x;  // vec4-element id
    const int dg  = v & 7;            // 4-elem group within head
    const int r16 = (v >> 3) & 15;    // row within fragment block
    const int u   = v >> 7;           // (h, nb) chunk id, 0..5119
    const int h   = u & 7;
    const int nb_all = u >> 3;        // 0..639
    const bool isS = nb_all < NB_S;
    const int nb  = isS ? nb_all : nb_all - NB_S;
    const int n   = nb * 16 + r16;    // source row within its tensor

    const float* src = isS ? s : ro;
    f32x4 x = *(const f32x4*)(src + (size_t)n * ROWLEN + h * HDIM + dg * 4);
    float ss = x[0] * x[0] + x[1] * x[1] + x[2] * x[2] + x[3] * x[3];
    ss += __shfl_xor(ss, 1);
    ss += __shfl_xor(ss, 2);
    ss += __shfl_xor(ss, 4);
    const float inv = rsqrtf(ss);
    s16x4 r;
    r[0] = f32_to_bf16_rne(x[0] * inv);
    r[1] = f32_to_bf16_rne(x[1] * inv);
    r[2] = f32_to_bf16_rne(x[2] * inv);
    r[3] = f32_to_bf16_rne(x[3] * inv);

    short* dst = isS ? sF : roF;
    const int NB = isS ? NB_S : NB_RO;
    *(s16x4*)(dst + ((size_t)(h * NB + nb) * 16 + r16) * 32 + dg * 4) = r;
}

// Wave tile 32x64 (s-rows x ro-cols) -- accumulator only 8 f32x4 = 32 VGPR,
// sized for occupancy (target >=4 waves/SIMD vs ~2 for the old 64x64 tile).
// Block = 4 waves stacked on rows -> 128x64 tile; the 4 waves share the
// B-fragments through L1. Grid = 16 x 128 = 2048 blocks.
// Per head: 2 A-frags + 4 B-frags (contiguous 1 KiB fragment-major loads),
// 8 MFMAs (16x16x32, K=32==HDIM, C=0), elementwise max into running max.
// mfma(B, A): D lane-axis (lane&15) = s-row, reg-axis = 4 consecutive
// ro-cols. Epilogue repacks via wave-private padded LDS so each store instr
// covers 4 rows x 256B.
__global__ __launch_bounds__(256) void mhd_dist(const short* __restrict__ sF,
                                                const short* __restrict__ roF,
                                                float* __restrict__ out) {
    __shared__ float lds[4][16][68];  // 68 = 64 + 4 pad
    const int lane = threadIdx.x & 63;
    const int wave = threadIdx.x >> 6;   // rows 32*wave .. +31
    const int tile_r = blockIdx.x >> 7;  // 16 row tiles of 128
    const int tile_c = blockIdx.x & 127; // 128 col tiles of 64
    const int l15 = lane & 15;
    const int kg = lane >> 4;

    const int nbA = tile_r * 8 + wave * 2;  // first s fragment-block (2 per wave)
    const int nbB = tile_c * 4;             // first ro fragment-block (4)
    const size_t laneOff = (size_t)l15 * 32 + kg * 8;

    f32x4 runmax[2][4];
#pragma unroll
    for (int i = 0; i < 2; ++i)
#pragma unroll
        for (int j = 0; j < 4; ++j)
            runmax[i][j] = (f32x4){-3.0e38f, -3.0e38f, -3.0e38f, -3.0e38f};

#pragma unroll 2
    for (int h = 0; h < HEADS; ++h) {
        const short* aBase = sF  + (size_t)(h * NB_S  + nbA) * 512 + laneOff;
        const short* bBase = roF + (size_t)(h * NB_RO + nbB) * 512 + laneOff;
        bf16x8 a[2], b[4];
#pragma unroll
        for (int i = 0; i < 2; ++i)
            a[i] = *(const bf16x8*)(aBase + (size_t)i * 512);
#pragma unroll
        for (int j = 0; j < 4; ++j)
            b[j] = *(const bf16x8*)(bBase + (size_t)j * 512);
#pragma unroll
        for (int i = 0; i < 2; ++i)
#pragma unroll
            for (int j = 0; j < 4; ++j) {
                f32x4 acc = {0.f, 0.f, 0.f, 0.f};
                acc = __builtin_amdgcn_mfma_f32_16x16x32_bf16(b[j], a[i], acc, 0, 0, 0);
#pragma unroll
                for (int q = 0; q < 4; ++q)
                    runmax[i][j][q] = fmaxf(runmax[i][j][q], acc[q]);
            }
    }

    // Epilogue: per 16-row chunk i, repack D-layout -> row-major via
    // wave-private LDS (no barrier needed; same-wave lgkmcnt ordering),
    // then 4 store instrs of 4 rows x 256B each.
    float* outBase = out + (size_t)(tile_r * 128 + wave * 32) * RO_ROWS
                         + tile_c * 64;
    const int srow = lane >> 4;        // 0..3: row within a 4-row store group
    const int scol = (lane & 15) * 4;  // f32 col within the 64-wide tile
#pragma unroll
    for (int i = 0; i < 2; ++i) {
#pragma unroll
        for (int j = 0; j < 4; ++j)
            *(f32x4*)&lds[wave][l15][kg * 4 + j * 16] = runmax[i][j];
#pragma unroll
        for (int t = 0; t < 4; ++t) {
            const int rowL = t * 4 + srow;
            f32x4 vv = *(const f32x4*)&lds[wave][rowL][scol];
            *(f32x4*)(outBase + (size_t)(i * 16 + rowL) * RO_ROWS + scol) = vv;
        }
    }
}

extern "C" void kernel_launch(void* const* d_in, const int* in_sizes, int n_in,
                              void* d_out, int out_size, void* d_ws, size_t ws_size,
                              hipStream_t stream) {
    const float* batch_s  = (const float*)d_in[0];
    const float* batch_ro = (const float*)d_in[1];
    float* out = (float*)d_out;

    short* sF  = (short*)d_ws;                  // 2048*256 bf16 = 1 MiB
    short* roF = sF + (size_t)S_ROWS * ROWLEN;  // 8192*256 bf16 = 4 MiB

    const int totalV4 = (S_ROWS + RO_ROWS) * ROWLEN / 4;   // 655360 (exact x256)
    mhd_normalize<<<totalV4 / 256, 256, 0, stream>>>(batch_s, batch_ro, sF, roF);

    mhd_dist<<<(S_ROWS / 128) * (RO_ROWS / 64), 256, 0, stream>>>(sF, roF, out);
}

// Round 9
// 97.613 us; speedup vs baseline: 1.0541x; 1.0541x over previous
//
#include <hip/hip_runtime.h>

#define S_ROWS 2048
#define RO_ROWS 8192
#define HEADS 8
#define HDIM 32
#define ROWLEN 256           // HEADS * HDIM
#define NB_S (S_ROWS / 16)   // 128 fragment-blocks of s
#define NB_RO (RO_ROWS / 16) // 512 fragment-blocks of ro

typedef __attribute__((ext_vector_type(8))) short bf16x8;
typedef __attribute__((ext_vector_type(4))) float f32x4;
typedef __attribute__((ext_vector_type(4))) short s16x4;

__device__ __forceinline__ short f32_to_bf16_rne(float f) {
    union { float f; unsigned u; } v; v.f = f;
    return (short)((v.u + 0x7fffu + ((v.u >> 16) & 1u)) >> 16);
}

// async global->LDS, 16B per lane: LDS dest = uniform base + lane*16 (HW),
// global src = per-lane (we add lane*16 at the call site).
__device__ __forceinline__ void gll16(const void* g, void* l) {
    __builtin_amdgcn_global_load_lds(
        (const __attribute__((address_space(1))) unsigned*)g,
        (__attribute__((address_space(3))) unsigned*)l, 16, 0, 0);
}

// Normalize every 32-elem head vector; emit bf16 fragments in LANE-LINEAR
// MFMA order: fragment (h, nb) is 1 KiB where byte offset lane*16 holds the
// 8 bf16 that MFMA lane `lane` consumes (row = lane&15, k = (lane>>4)*8..+7).
// This makes the dist kernel's global->LDS staging a pure linear copy
// (global_load_lds pattern) and its ds_read_b128 conflict-free.
// Thread (v): dg = k-group (4 elems), r16 = row in fragment. Threads sharing
// a head vector differ only in dg = v&7 -> shfl_xor 1/2/4 reduces the norm.
__global__ __launch_bounds__(256) void mhd_normalize(const float* __restrict__ s,
                                                     const float* __restrict__ ro,
                                                     short* __restrict__ sF,
                                                     short* __restrict__ roF) {
    const int v   = blockIdx.x * 256 + threadIdx.x;  // vec4-element id
    const int dg  = v & 7;            // k-elems dg*4 .. dg*4+3
    const int r16 = (v >> 3) & 15;    // row within fragment block
    const int u   = v >> 7;           // (h, nb) chunk id
    const int h   = u & 7;
    const int nb_all = u >> 3;        // 0..639
    const bool isS = nb_all < NB_S;
    const int nb  = isS ? nb_all : nb_all - NB_S;
    const int n   = nb * 16 + r16;    // source row within its tensor

    const float* src = isS ? s : ro;
    f32x4 x = *(const f32x4*)(src + (size_t)n * ROWLEN + h * HDIM + dg * 4);
    float ss = x[0] * x[0] + x[1] * x[1] + x[2] * x[2] + x[3] * x[3];
    ss += __shfl_xor(ss, 1);
    ss += __shfl_xor(ss, 2);
    ss += __shfl_xor(ss, 4);
    const float inv = rsqrtf(ss);
    s16x4 r;
    r[0] = f32_to_bf16_rne(x[0] * inv);
    r[1] = f32_to_bf16_rne(x[1] * inv);
    r[2] = f32_to_bf16_rne(x[2] * inv);
    r[3] = f32_to_bf16_rne(x[3] * inv);

    short* dst = isS ? sF : roF;
    const int NB = isS ? NB_S : NB_RO;
    // lane-linear: lane = (dg>>1)*16 + r16, 16B half = dg&1
    const int lane_in_frag = ((dg >> 1) << 4) + r16;
    const size_t off = ((size_t)(h * NB + nb) << 9) + lane_in_frag * 8 + (dg & 1) * 4;
    *(s16x4*)(dst + off) = r;
}

// Block tile 256x128 (s-rows x ro-cols), 8 waves (4x2 of 64x64 wave tiles),
// grid 8x64 = 512 blocks (2 blocks/CU). Per head: 16 A-frags + 8 B-frags
// staged ONCE per block into LDS (global_load_lds, 1 KiB per wave-instr,
// 3 frags/wave), double-buffered over heads (catalog T3 minimal 2-phase).
// Chip-wide global reads drop 256 MiB -> 96 MiB. ds_read_b128 at
// base+lane*16 = conflict-free lane-linear fragments.
// mfma(B, A): D lane-axis (lane&15) = s-row, reg-axis = 4 consecutive
// ro-cols. Epilogue repacks via per-wave padded LDS (after final barrier)
// so each store instr covers 4 rows x 256B.
__global__ __launch_bounds__(512, 4) void mhd_dist(const short* __restrict__ sF,
                                                   const short* __restrict__ roF,
                                                   float* __restrict__ out) {
    __shared__ short lds[2][24 * 512];   // 2 bufs x (16 A + 8 B) KiB = 48 KiB
    const int lane = threadIdx.x & 63;
    const int wave = threadIdx.x >> 6;   // 0..7
    const int wr = wave >> 1;            // 0..3: 64-row strip
    const int wc = wave & 1;             // 0..1: 64-col strip
    const int tile_r = blockIdx.x >> 6;  // 8 row tiles of 256
    const int tile_c = blockIdx.x & 63;  // 64 col tiles of 128
    const int nbA0 = tile_r * 16;
    const int nbB0 = tile_c * 8;

    // staging sources: wave stages fragments f = wave*3 .. wave*3+2
    // (f<16: A frag f; f>=16: B frag f-16); per-lane src = base + lane*16B
    const short* gsrc[3];
    size_t hstep[3];
#pragma unroll
    for (int t = 0; t < 3; ++t) {
        const int f = wave * 3 + t;
        if (f < 16) {
            gsrc[t] = sF + ((size_t)(nbA0 + f) << 9) + lane * 8;
            hstep[t] = (size_t)NB_S << 9;
        } else {
            gsrc[t] = roF + ((size_t)(nbB0 + (f - 16)) << 9) + lane * 8;
            hstep[t] = (size_t)NB_RO << 9;
        }
    }

    f32x4 rmax[4][4];
#pragma unroll
    for (int i = 0; i < 4; ++i)
#pragma unroll
        for (int j = 0; j < 4; ++j)
            rmax[i][j] = (f32x4){-3.0e38f, -3.0e38f, -3.0e38f, -3.0e38f};

    // prologue: stage head 0 into buf 0
#pragma unroll
    for (int t = 0; t < 3; ++t)
        gll16(gsrc[t], &lds[0][(wave * 3 + t) * 512]);
    __syncthreads();

#pragma unroll 1
    for (int h = 0; h < HEADS; ++h) {
        const int buf = h & 1;
        if (h < HEADS - 1) {
#pragma unroll
            for (int t = 0; t < 3; ++t)
                gll16(gsrc[t] + (size_t)(h + 1) * hstep[t],
                      &lds[buf ^ 1][(wave * 3 + t) * 512]);
        }
        bf16x8 a[4], b[4];
#pragma unroll
        for (int i = 0; i < 4; ++i)
            a[i] = *(const bf16x8*)&lds[buf][(wr * 4 + i) * 512 + lane * 8];
#pragma unroll
        for (int j = 0; j < 4; ++j)
            b[j] = *(const bf16x8*)&lds[buf][(16 + wc * 4 + j) * 512 + lane * 8];
#pragma unroll
        for (int i = 0; i < 4; ++i)
#pragma unroll
            for (int j = 0; j < 4; ++j) {
                f32x4 acc = {0.f, 0.f, 0.f, 0.f};
                acc = __builtin_amdgcn_mfma_f32_16x16x32_bf16(b[j], a[i], acc, 0, 0, 0);
#pragma unroll
                for (int q = 0; q < 4; ++q)
                    rmax[i][j][q] = fmaxf(rmax[i][j][q], acc[q]);
            }
        __syncthreads();   // drains stage(h+1); protects buf reuse next iter
    }

    // Epilogue: final loop barrier ensures all staging/reads done -> reuse
    // LDS as per-wave padded [16][68] f32 repack buffers (wave-private, no
    // barriers; same-wave lgkmcnt orders write->read).
    float* eld = (float*)&lds[0][0] + wave * 16 * 68;
    const int l15 = lane & 15;
    const int kg = lane >> 4;
    float* outBase = out + (size_t)(tile_r * 256 + wr * 64) * RO_ROWS
                         + tile_c * 128 + wc * 64;
    const int srow = lane >> 4;        // 0..3: row within a 4-row store group
    const int scol = (lane & 15) * 4;  // f32 col within the 64-wide tile
#pragma unroll
    for (int i = 0; i < 4; ++i) {
#pragma unroll
        for (int j = 0; j < 4; ++j)
            *(f32x4*)&eld[l15 * 68 + kg * 4 + j * 16] = rmax[i][j];
#pragma unroll
        for (int t = 0; t < 4; ++t) {
            const int rowL = t * 4 + srow;
            f32x4 vv = *(const f32x4*)&eld[rowL * 68 + scol];
            *(f32x4*)(outBase + (size_t)(i * 16 + rowL) * RO_ROWS + scol) = vv;
        }
    }
}

extern "C" void kernel_launch(void* const* d_in, const int* in_sizes, int n_in,
                              void* d_out, int out_size, void* d_ws, size_t ws_size,
                              hipStream_t stream) {
    const float* batch_s  = (const float*)d_in[0];
    const float* batch_ro = (const float*)d_in[1];
    float* out = (float*)d_out;

    short* sF  = (short*)d_ws;                  // 2048*256 bf16 = 1 MiB
    short* roF = sF + (size_t)S_ROWS * ROWLEN;  // 8192*256 bf16 = 4 MiB

    const int totalV4 = (S_ROWS + RO_ROWS) * ROWLEN / 4;   // 655360 (exact x256)
    mhd_normalize<<<totalV4 / 256, 256, 0, stream>>>(batch_s, batch_ro, sF, roF);

    mhd_dist<<<(S_ROWS / 256) * (RO_ROWS / 128), 512, 0, stream>>>(sF, roF, out);
}

// Round 10
// 95.937 us; speedup vs baseline: 1.0725x; 1.0175x over previous
//
#include <hip/hip_runtime.h>

#define S_ROWS 2048
#define RO_ROWS 8192
#define HEADS 8
#define HDIM 32
#define ROWLEN 256           // HEADS * HDIM
#define NB_S (S_ROWS / 16)   // 128 fragment-blocks of s
#define NB_RO (RO_ROWS / 16) // 512 fragment-blocks of ro

typedef __attribute__((ext_vector_type(8))) short bf16x8;
typedef __attribute__((ext_vector_type(4))) float f32x4;
typedef __attribute__((ext_vector_type(4))) short s16x4;

__device__ __forceinline__ short f32_to_bf16_rne(float f) {
    union { float f; unsigned u; } v; v.f = f;
    return (short)((v.u + 0x7fffu + ((v.u >> 16) & 1u)) >> 16);
}

// Normalize every 32-elem head vector; emit bf16 fragments in LANE-LINEAR
// MFMA order: fragment (h, nb) is 1 KiB where byte offset lane*16 holds the
// 8 bf16 that MFMA lane `lane` consumes (row = lane&15, k = (lane>>4)*8..+7).
// Dist then loads operands as frag_base + lane*16B — fully coalesced 1 KiB
// per wave-instruction.
__global__ __launch_bounds__(256) void mhd_normalize(const float* __restrict__ s,
                                                     const float* __restrict__ ro,
                                                     short* __restrict__ sF,
                                                     short* __restrict__ roF) {
    const int v   = blockIdx.x * 256 + threadIdx.x;  // vec4-element id
    const int dg  = v & 7;            // k-elems dg*4 .. dg*4+3
    const int r16 = (v >> 3) & 15;    // row within fragment block
    const int u   = v >> 7;           // (h, nb) chunk id
    const int h   = u & 7;
    const int nb_all = u >> 3;        // 0..639
    const bool isS = nb_all < NB_S;
    const int nb  = isS ? nb_all : nb_all - NB_S;
    const int n   = nb * 16 + r16;    // source row within its tensor

    const float* src = isS ? s : ro;
    f32x4 x = *(const f32x4*)(src + (size_t)n * ROWLEN + h * HDIM + dg * 4);
    float ss = x[0] * x[0] + x[1] * x[1] + x[2] * x[2] + x[3] * x[3];
    ss += __shfl_xor(ss, 1);
    ss += __shfl_xor(ss, 2);
    ss += __shfl_xor(ss, 4);
    const float inv = rsqrtf(ss);
    s16x4 r;
    r[0] = f32_to_bf16_rne(x[0] * inv);
    r[1] = f32_to_bf16_rne(x[1] * inv);
    r[2] = f32_to_bf16_rne(x[2] * inv);
    r[3] = f32_to_bf16_rne(x[3] * inv);

    short* dst = isS ? sF : roF;
    const int NB = isS ? NB_S : NB_RO;
    // lane-linear: lane = (dg>>1)*16 + r16, 16B half = dg&1
    const int lane_in_frag = ((dg >> 1) << 4) + r16;
    const size_t off = ((size_t)(h * NB + nb) << 9) + lane_in_frag * 8 + (dg & 1) * 4;
    *(s16x4*)(dst + off) = r;
}

// XCD-strip design (traffic-model test): bid&7 -> XCD (dispatch round-robin
// heuristic); each XCD owns ONE contiguous 256-row output strip. Its
// s-strip fragments (128 KiB) stay L2-resident; ro is streamed once per XCD
// (col-tiles sequential in bid>>3) -> chip-wide L3-level reads ~33 MiB
// (vs 96 MiB in the LDS-staged version, which measured identically to the
// no-LDS version -> staging is not the lever; traffic is the hypothesis).
// Block tile 256x128, 8 waves (4x2 of 64x64), register-direct fragment
// loads (4 KiB contiguous per side per head), NO main-loop barriers.
// mfma(B, A): D lane-axis (lane&15) = s-row, reg-axis = 4 consecutive
// ro-cols. Epilogue repacks via per-wave padded LDS so each store instr
// covers 4 rows x 256B (proven R4/R9 epilogue, unchanged).
__global__ __launch_bounds__(512, 4) void mhd_dist(const short* __restrict__ sF,
                                                   const short* __restrict__ roF,
                                                   float* __restrict__ out) {
    __shared__ float elds[8][16][68];     // per-wave repack, 34.8 KiB
    const int lane = threadIdx.x & 63;
    const int wave = threadIdx.x >> 6;    // 0..7
    const int wr = wave >> 1;             // 0..3: 64-row strip in block
    const int wc = wave & 1;              // 0..1: 64-col strip in block
    const int xcd = blockIdx.x & 7;       // strip id == XCD (heuristic)
    const int q   = blockIdx.x >> 3;      // 0..63: col tile of 128
    const int nbA = xcd * 16 + wr * 4;    // first s fragment-block
    const int nbB = q * 8 + wc * 4;       // first ro fragment-block
    const size_t laneOff = (size_t)lane * 8;   // shorts: lane*16B

    f32x4 rmax[4][4];
#pragma unroll
    for (int i = 0; i < 4; ++i)
#pragma unroll
        for (int j = 0; j < 4; ++j)
            rmax[i][j] = (f32x4){-3.0e38f, -3.0e38f, -3.0e38f, -3.0e38f};

#pragma unroll 1
    for (int h = 0; h < HEADS; ++h) {
        const short* aBase = sF  + ((size_t)(h * NB_S  + nbA) << 9) + laneOff;
        const short* bBase = roF + ((size_t)(h * NB_RO + nbB) << 9) + laneOff;
        bf16x8 a[4], b[4];
#pragma unroll
        for (int i = 0; i < 4; ++i) {
            a[i] = *(const bf16x8*)(aBase + ((size_t)i << 9));
            b[i] = *(const bf16x8*)(bBase + ((size_t)i << 9));
        }
#pragma unroll
        for (int i = 0; i < 4; ++i)
#pragma unroll
            for (int j = 0; j < 4; ++j) {
                f32x4 acc = {0.f, 0.f, 0.f, 0.f};
                acc = __builtin_amdgcn_mfma_f32_16x16x32_bf16(b[j], a[i], acc, 0, 0, 0);
#pragma unroll
                for (int q2 = 0; q2 < 4; ++q2)
                    rmax[i][j][q2] = fmaxf(rmax[i][j][q2], acc[q2]);
            }
    }

    // Epilogue: per 16-row chunk i, repack D-layout -> row-major via
    // wave-private LDS (no barriers; same-wave lgkmcnt orders write->read),
    // then 4 store instrs of 4 rows x 256B each.
    const int l15 = lane & 15;
    const int kg = lane >> 4;
    float* outBase = out + (size_t)(xcd * 256 + wr * 64) * RO_ROWS
                         + q * 128 + wc * 64;
    const int srow = lane >> 4;        // 0..3: row within a 4-row store group
    const int scol = (lane & 15) * 4;  // f32 col within the 64-wide tile
#pragma unroll
    for (int i = 0; i < 4; ++i) {
#pragma unroll
        for (int j = 0; j < 4; ++j)
            *(f32x4*)&elds[wave][l15][kg * 4 + j * 16] = rmax[i][j];
#pragma unroll
        for (int t = 0; t < 4; ++t) {
            const int rowL = t * 4 + srow;
            f32x4 vv = *(const f32x4*)&elds[wave][rowL][scol];
            *(f32x4*)(outBase + (size_t)(i * 16 + rowL) * RO_ROWS + scol) = vv;
        }
    }
}

extern "C" void kernel_launch(void* const* d_in, const int* in_sizes, int n_in,
                              void* d_out, int out_size, void* d_ws, size_t ws_size,
                              hipStream_t stream) {
    const float* batch_s  = (const float*)d_in[0];
    const float* batch_ro = (const float*)d_in[1];
    float* out = (float*)d_out;

    short* sF  = (short*)d_ws;                  // 2048*256 bf16 = 1 MiB
    short* roF = sF + (size_t)S_ROWS * ROWLEN;  // 8192*256 bf16 = 4 MiB

    const int totalV4 = (S_ROWS + RO_ROWS) * ROWLEN / 4;   // 655360 (exact x256)
    mhd_normalize<<<totalV4 / 256, 256, 0, stream>>>(batch_s, batch_ro, sF, roF);

    // 512 blocks: bit0-2 = XCD/strip, rest = col tile (ro streamed in order)
    mhd_dist<<<(S_ROWS / 256) * (RO_ROWS / 128), 512, 0, stream>>>(sF, roF, out);
}